// Round 5
// baseline (555.278 us; speedup 1.0000x reference)
//
#include <hip/hip_runtime.h>
#include <hip/hip_bf16.h>
#include <cstdint>
#include <cstddef>

#define HW     16384      // H*W
#define WIDTH  128
#define NB     2
#define NTOPK  300
#define JUNC_TH 0.008f

typedef __attribute__((ext_vector_type(8))) short s16x8;
typedef __attribute__((ext_vector_type(4))) float f32x4;
typedef __attribute__((ext_vector_type(4))) unsigned int u32x4;

// ---------------------------------------------------------------- utilities
__device__ __forceinline__ float sigm(float x) { return 1.0f / (1.0f + expf(-x)); }

__device__ __forceinline__ unsigned short f2bf(float f) {
  __hip_bfloat16 h = __float2bfloat16(f);
  return __hip_bfloat16_raw(h).x;
}
__device__ __forceinline__ float bf2f(unsigned short u) {
  __hip_bfloat16_raw r; r.x = u;
  return __bfloat162float(__hip_bfloat16(r));
}
__device__ __forceinline__ float2 bf2x2(unsigned int u) {
  return make_float2(__uint_as_float(u << 16), __uint_as_float(u & 0xffff0000u));
}

// ---------------------------------------------------------------- W transpose (256x128 <- 128x256), fp32
__global__ void k_transpose_w(const float* __restrict__ w, float* __restrict__ wt) {
  int i = blockIdx.x * 256 + threadIdx.x;   // 32768
  int d = i & 127, c = i >> 7;
  wt[c * 128 + d] = w[d * 256 + c];
}

// ---------------------------------------------------------------- FC weight transpose+cast: wt_bf16[n][k] = w[k][n]
__global__ __launch_bounds__(256) void k_wtrans(const float* __restrict__ w,
                                                unsigned short* __restrict__ wt) {
  __shared__ float tile[32][33];
  int n0 = blockIdx.x * 32, k0 = blockIdx.y * 32;
  int tx = threadIdx.x & 31, ty = threadIdx.x >> 5;   // 32 x 8
#pragma unroll
  for (int r = 0; r < 32; r += 8)
    tile[ty + r][tx] = w[(size_t)(k0 + ty + r) * 1024 + n0 + tx];
  __syncthreads();
#pragma unroll
  for (int r = 0; r < 32; r += 8)
    wt[(size_t)(n0 + ty + r) * 1024 + k0 + tx] = f2bf(tile[tx][ty + r]);
}

// ---------------------------------------------------------------- loi GEMM (fp32 math, bf16 store): loi_t[b][p][d]
__global__ __launch_bounds__(256) void k_loi(const float* __restrict__ F,
                                             const float* __restrict__ wt,
                                             const float* __restrict__ bias,
                                             unsigned short* __restrict__ loi) {
  int b = blockIdx.y;
  int p0 = blockIdx.x * 64;
  __shared__ float As[8][64];
  __shared__ float Bs[8][128];
  int t = threadIdx.x;
  int tn = t & 15;    // n group: n = tn*8
  int tm = t >> 4;    // m group: m = tm*4
  float acc[4][8];
#pragma unroll
  for (int i = 0; i < 4; ++i)
#pragma unroll
    for (int j = 0; j < 8; ++j) acc[i][j] = 0.0f;

  const float* Fb = F + (size_t)b * 256 * HW;
  for (int c0 = 0; c0 < 256; c0 += 8) {
    __syncthreads();
    if (t < 128) {
      int kk = t >> 4, mv = t & 15;
      float4 v = *(const float4*)(Fb + (size_t)(c0 + kk) * HW + p0 + mv * 4);
      *(float4*)&As[kk][mv * 4] = v;
    }
    {
      int kk = t >> 5, dv = t & 31;
      float4 v = *(const float4*)(wt + (size_t)(c0 + kk) * 128 + dv * 4);
      *(float4*)&Bs[kk][dv * 4] = v;
    }
    __syncthreads();
#pragma unroll
    for (int kk = 0; kk < 8; ++kk) {
      float4 a4 = *(const float4*)&As[kk][tm * 4];
      float4 b0 = *(const float4*)&Bs[kk][tn * 8];
      float4 b1 = *(const float4*)&Bs[kk][tn * 8 + 4];
      float av[4] = {a4.x, a4.y, a4.z, a4.w};
      float bv[8] = {b0.x, b0.y, b0.z, b0.w, b1.x, b1.y, b1.z, b1.w};
#pragma unroll
      for (int i = 0; i < 4; ++i)
#pragma unroll
        for (int j = 0; j < 8; ++j) acc[i][j] += av[i] * bv[j];
    }
  }
  float4 c0v = *(const float4*)(bias + tn * 8);
  float4 c1v = *(const float4*)(bias + tn * 8 + 4);
  float bb[8] = {c0v.x, c0v.y, c0v.z, c0v.w, c1v.x, c1v.y, c1v.z, c1v.w};
#pragma unroll
  for (int i = 0; i < 4; ++i) {
    int p = p0 + tm * 4 + i;
    alignas(16) unsigned short o[8];
#pragma unroll
    for (int j = 0; j < 8; ++j) o[j] = f2bf(acc[i][j] + bb[j]);
    *(s16x8*)(loi + ((size_t)b * HW + p) * 128 + tn * 8) = *(const s16x8*)o;
  }
}

// ---------------------------------------------------------------- jloc = softmax(out9[5:7])[1]
__global__ void k_jloc(const float* __restrict__ out9, float* __restrict__ jloc) {
  int i = blockIdx.x * 256 + threadIdx.x;    // NB*HW
  int b = i >> 14, p = i & (HW - 1);
  const float* base = out9 + (size_t)b * 9 * HW;
  float o5 = base[5 * HW + p], o6 = base[6 * HW + p];
  float m = fmaxf(o5, o6);
  float e5 = expf(o5 - m), e6 = expf(o6 - m);
  jloc[i] = e6 / (e5 + e6);
}

// ---------------------------------------------------------------- NMS + sortable key
__global__ void k_nmskey(const float* __restrict__ jloc, unsigned long long* __restrict__ keys) {
  int i = blockIdx.x * 256 + threadIdx.x;
  int b = i >> 14, p = i & (HW - 1);
  int y = p >> 7, x = p & 127;
  const float* J = jloc + (size_t)b * HW;
  float c = J[p];
  float m = c;
  for (int dy = -1; dy <= 1; ++dy) {
    int yy = y + dy;
    if (yy < 0 || yy > 127) continue;
    for (int dx = -1; dx <= 1; ++dx) {
      int xx = x + dx;
      if (xx < 0 || xx > 127) continue;
      m = fmaxf(m, J[yy * WIDTH + xx]);
    }
  }
  unsigned int vb = (c == m) ? __float_as_uint(c) : 0u;   // jloc > 0 always -> bits monotone
  keys[i] = ((unsigned long long)vb << 32) | (unsigned int)(~p);
}

// ---------------------------------------------------------------- top-300 per image via bitonic sort (1 block/image)
__global__ __launch_bounds__(1024) void k_topk(const unsigned long long* __restrict__ keys,
                                               const float* __restrict__ out9,
                                               float* __restrict__ jx, float* __restrict__ jy) {
  int b = blockIdx.x;
  __shared__ unsigned long long cand[4096];
  __shared__ int cnt;
  int t = threadIdx.x;
  if (t == 0) cnt = 0;
#pragma unroll
  for (int i = t; i < 4096; i += 1024) cand[i] = 0ull;
  __syncthreads();
  const unsigned long long* K = keys + (size_t)b * HW;
  for (int i = t; i < HW; i += 1024) {
    unsigned long long k = K[i];
    if ((k >> 32) != 0ull) {
      int pos = atomicAdd(&cnt, 1);
      if (pos < 4096) cand[pos] = k;
    }
  }
  __syncthreads();
  // bitonic sort, descending (keys distinct except zero-padding)
  for (int k = 2; k <= 4096; k <<= 1) {
    for (int j = k >> 1; j > 0; j >>= 1) {
#pragma unroll
      for (int idx = t; idx < 4096; idx += 1024) {
        int ixj = idx ^ j;
        if (ixj > idx) {
          unsigned long long a = cand[idx], c = cand[ixj];
          bool up = ((idx & k) == 0);
          if (up ? (a < c) : (a > c)) { cand[idx] = c; cand[ixj] = a; }
        }
      }
      __syncthreads();
    }
  }
  if (t < NTOPK) {
    const float* o7 = out9 + (size_t)b * 9 * HW + 7 * HW;
    const float* o8 = out9 + (size_t)b * 9 * HW + 8 * HW;
    unsigned long long bb = cand[t];
    unsigned int vb = (unsigned int)(bb >> 32);
    float val = __uint_as_float(vb);
    if (vb != 0u && val > JUNC_TH) {
      int p = (int)(~((unsigned int)(bb & 0xffffffffull))) & (HW - 1);
      float ox = sigm(o7[p]) - 0.5f;
      float oy = sigm(o8[p]) - 0.5f;
      jx[b * NTOPK + t] = (float)(p & 127) + ox + 0.5f;
      jy[b * NTOPK + t] = (float)(p >> 7) + oy + 0.5f;
    } else {
      jx[b * NTOPK + t] = 1000000.0f;
      jy[b * NTOPK + t] = 1000000.0f;
    }
  }
}

// ---------------------------------------------------------------- per-line argmin assignment + lines2 output (+ logits zero)
__global__ __launch_bounds__(256) void k_lines(const float* __restrict__ lp,
                                               const float* __restrict__ jx,
                                               const float* __restrict__ jy,
                                               float4* __restrict__ lines4,
                                               int* __restrict__ iskeep,
                                               float* __restrict__ out_lines,
                                               float* __restrict__ logits) {
  int b = blockIdx.y;
  int l = blockIdx.x * 256 + threadIdx.x;
  __shared__ float jxs[NTOPK], jys[NTOPK];
  for (int i = threadIdx.x; i < NTOPK; i += 256) {
    jxs[i] = jx[b * NTOPK + i];
    jys[i] = jy[b * NTOPK + i];
  }
  __syncthreads();
  int gl = b * HW + l;
  const float* L = lp + (size_t)gl * 4;
  float x1 = L[0], y1 = L[1], x2 = L[2], y2 = L[3];
  float bd1 = 3.4e38f, bd2 = 3.4e38f;
  int i1 = 0, i2 = 0;
  for (int j = 0; j < NTOPK; ++j) {
    float ax = __fsub_rn(x1, jxs[j]);
    float ay = __fsub_rn(y1, jys[j]);
    float d1 = __fadd_rn(__fmul_rn(ax, ax), __fmul_rn(ay, ay));
    if (d1 < bd1) { bd1 = d1; i1 = j; }
    float ex = __fsub_rn(x2, jxs[j]);
    float ey = __fsub_rn(y2, jys[j]);
    float d2 = __fadd_rn(__fmul_rn(ex, ex), __fmul_rn(ey, ey));
    if (d2 < bd2) { bd2 = d2; i2 = j; }
  }
  int imin = min(i1, i2), imax = max(i1, i2);
  float sx1 = jxs[imin], sy1 = jys[imin], sx2 = jxs[imax], sy2 = jys[imax];
  lines4[gl] = make_float4(sx1, sy1, sx2, sy2);
  iskeep[gl] = (imin < imax) ? 1 : 0;
  logits[gl] = 0.0f;
  ((float4*)out_lines)[gl] = make_float4(sx1 * 4.0f, sy1 * 4.0f, sx2 * 4.0f, sy2 * 4.0f);
}

// ---------------------------------------------------------------- bilinear sample + maxpool
// 2 lines per block, 128 threads: t>>6 = line-in-block, t&63 = channel pair.
__global__ __launch_bounds__(128) void k_sample(const unsigned short* __restrict__ loi,
                                                const float4* __restrict__ lines4,
                                                unsigned short* __restrict__ xvec,
                                                int b, int l0) {
  __shared__ int   soff[2][32][4];
  __shared__ float swt[2][32][4];
  int t = threadIdx.x;
  if (t < 64) {
    int li = t >> 5, k = t & 31;
    int l = l0 + blockIdx.x * 2 + li;
    float4 ln = lines4[b * HW + l];
    float tt = (float)k * (1.0f / 31.0f);
    float tc = 1.0f - tt;
    float px = ln.x * tt + ln.z * tc - 0.5f;
    float py = ln.y * tt + ln.w * tc - 0.5f;
    float px0 = fminf(fmaxf(floorf(px), 0.0f), 127.0f);
    float py0 = fminf(fmaxf(floorf(py), 0.0f), 127.0f);
    float px1 = fminf(px0 + 1.0f, 127.0f);
    float py1 = fminf(py0 + 1.0f, 127.0f);
    int ix0 = (int)px0, iy0 = (int)py0, ix1 = (int)px1, iy1 = (int)py1;
    float wy1 = __fsub_rn(py1, py), wy0 = __fsub_rn(py, py0);
    float wx1 = __fsub_rn(px1, px), wx0 = __fsub_rn(px, px0);
    soff[li][k][0] = (iy0 * WIDTH + ix0) * 128;
    soff[li][k][1] = (iy1 * WIDTH + ix0) * 128;
    soff[li][k][2] = (iy0 * WIDTH + ix1) * 128;
    soff[li][k][3] = (iy1 * WIDTH + ix1) * 128;
    swt[li][k][0] = __fmul_rn(wy1, wx1);   // wa -> r00
    swt[li][k][1] = __fmul_rn(wy0, wx1);   // wb -> r10
    swt[li][k][2] = __fmul_rn(wy1, wx0);   // wc -> r01
    swt[li][k][3] = __fmul_rn(wy0, wx0);   // wd -> r11
  }
  __syncthreads();
  int li = t >> 6, c2 = t & 63;            // channels 2*c2, 2*c2+1
  int l = l0 + blockIdx.x * 2 + li;
  const unsigned short* Lb = loi + (size_t)b * HW * 128 + (c2 << 1);
  float rm0 = -3.4e38f, rm1 = -3.4e38f;
  alignas(16) unsigned short outv[16];
#pragma unroll 4
  for (int k = 0; k < 32; ++k) {
    int4   o = *(const int4*)soff[li][k];
    float4 w = *(const float4*)swt[li][k];
    unsigned int u0 = *(const unsigned int*)(Lb + o.x);
    unsigned int u1 = *(const unsigned int*)(Lb + o.y);
    unsigned int u2 = *(const unsigned int*)(Lb + o.z);
    unsigned int u3 = *(const unsigned int*)(Lb + o.w);
    float2 v0 = bf2x2(u0), v1 = bf2x2(u1), v2 = bf2x2(u2), v3 = bf2x2(u3);
    float a0 = __fadd_rn(__fadd_rn(__fadd_rn(__fmul_rn(v0.x, w.x), __fmul_rn(v1.x, w.y)),
                                   __fmul_rn(v2.x, w.z)), __fmul_rn(v3.x, w.w));
    float a1 = __fadd_rn(__fadd_rn(__fadd_rn(__fmul_rn(v0.y, w.x), __fmul_rn(v1.y, w.y)),
                                   __fmul_rn(v2.y, w.z)), __fmul_rn(v3.y, w.w));
    rm0 = fmaxf(rm0, a0);
    rm1 = fmaxf(rm1, a1);
    if ((k & 3) == 3) {
      outv[k >> 2]       = f2bf(rm0);
      outv[8 + (k >> 2)] = f2bf(rm1);
      rm0 = -3.4e38f; rm1 = -3.4e38f;
    }
  }
  unsigned short* dst = xvec + (size_t)(l - l0) * 1024 + c2 * 16;
  *(s16x8*)dst       = *(const s16x8*)outv;
  *(s16x8*)(dst + 8) = *(const s16x8*)(outv + 8);
}

// ---------------------------------------------------------------- shared FC K-loop: register-staged pipeline (prefetch distance 2)
// Plain global loads -> VGPR, ds_write_b128 -> ping-pong LDS. The barrier only
// needs lgkmcnt (LDS) drain; VGPR-targeted global loads stay in flight across it.
__device__ __forceinline__ void fc_kloop(const unsigned short* __restrict__ A,
                                         const unsigned short* __restrict__ Bt,
                                         short* sm, int m0, int n0,
                                         f32x4 acc[4][4]) {
  const int K = 1024;
  int t = threadIdx.x, lane = t & 63, w = t >> 6;
  int wm = w & 1, wn = w >> 1;
  int lr = lane & 15, ls = lane >> 4;

  const unsigned short* gA0 = A + (size_t)(m0 + w * 16 + lr) * K + ls * 8;
  const unsigned short* gA1 = A + (size_t)(m0 + (w + 4) * 16 + lr) * K + ls * 8;
  const unsigned short* gB0 = Bt + (size_t)(n0 + w * 16 + lr) * K + ls * 8;
  const unsigned short* gB1 = Bt + (size_t)(n0 + (w + 4) * 16 + lr) * K + ls * 8;
  int oA0 = w * 512 + lane * 8;
  int oA1 = (w + 4) * 512 + lane * 8;
  int oB0 = oA0 + 4096, oB1 = oA1 + 4096;

  // prologue: tile 0 -> LDS buf0 (through regs); issue tile 1 loads
  u32x4 ra0 = *(const u32x4*)gA0, ra1 = *(const u32x4*)gA1;
  u32x4 rb0 = *(const u32x4*)gB0, rb1 = *(const u32x4*)gB1;
  *(u32x4*)(sm + oA0) = ra0; *(u32x4*)(sm + oA1) = ra1;
  *(u32x4*)(sm + oB0) = rb0; *(u32x4*)(sm + oB1) = rb1;
  ra0 = *(const u32x4*)(gA0 + 32); ra1 = *(const u32x4*)(gA1 + 32);
  rb0 = *(const u32x4*)(gB0 + 32); rb1 = *(const u32x4*)(gB1 + 32);
  __syncthreads();

  int cur = 0;
#pragma unroll 2
  for (int k = 0; k < 32; ++k) {
    // issue tile k+2 loads (wrap at tail; junk data never consumed meaningfully)
    int k2 = ((k + 2) & 31) * 32;
    u32x4 sa0 = *(const u32x4*)(gA0 + k2), sa1 = *(const u32x4*)(gA1 + k2);
    u32x4 sb0 = *(const u32x4*)(gB0 + k2), sb1 = *(const u32x4*)(gB1 + k2);

    const short* As = sm + cur * 8192;
    const short* Bs = As + 4096;
    s16x8 af[4], bfr[4];
#pragma unroll
    for (int mi = 0; mi < 4; ++mi) af[mi] = *(const s16x8*)(As + (wm * 4 + mi) * 512 + lane * 8);
#pragma unroll
    for (int ni = 0; ni < 4; ++ni) bfr[ni] = *(const s16x8*)(Bs + (wn * 4 + ni) * 512 + lane * 8);
#pragma unroll
    for (int mi = 0; mi < 4; ++mi)
#pragma unroll
      for (int ni = 0; ni < 4; ++ni)
        acc[mi][ni] = __builtin_amdgcn_mfma_f32_16x16x32_bf16(af[mi], bfr[ni], acc[mi][ni], 0, 0, 0);

    // stage tile k+1 into the other buffer (vmcnt wait here, ~1 iter of flight)
    int nxt = cur ^ 1;
    short* d = sm + nxt * 8192;
    *(u32x4*)(d + oA0) = ra0; *(u32x4*)(d + oA1) = ra1;
    *(u32x4*)(d + oB0) = rb0; *(u32x4*)(d + oB1) = rb1;
    __syncthreads();
    cur = nxt;
    ra0 = sa0; ra1 = sa1; rb0 = sb0; rb1 = sb1;
  }
}

// ---------------------------------------------------------------- fc1: C = relu(A @ Bt^T + bias), bf16 out
__global__ __launch_bounds__(256) void k_fc1(const unsigned short* __restrict__ A,
                                             const unsigned short* __restrict__ Bt,
                                             const float* __restrict__ bias,
                                             unsigned short* __restrict__ C) {
  const int N = 1024;
  __shared__ __align__(16) short sm[17408];   // loop: 2x8192; epilogue: 128x136
  int t = threadIdx.x, lane = t & 63, w = t >> 6;
  int wm = w & 1, wn = w >> 1;
  int lr = lane & 15, ls = lane >> 4;
  int m0 = blockIdx.x * 128, n0 = blockIdx.y * 128;

  f32x4 acc[4][4];
#pragma unroll
  for (int i = 0; i < 4; ++i)
#pragma unroll
    for (int j = 0; j < 4; ++j) acc[i][j] = (f32x4){0.f, 0.f, 0.f, 0.f};

  fc_kloop(A, Bt, sm, m0, n0, acc);
  __syncthreads();

  // epilogue: stage C tile in LDS (stride 136 shorts), then coalesced stores
#pragma unroll
  for (int ni = 0; ni < 4; ++ni) {
    int cl = wn * 64 + ni * 16 + lr;
    float bv = bias[n0 + cl];
#pragma unroll
    for (int mi = 0; mi < 4; ++mi) {
      int rl = wm * 64 + mi * 16 + ls * 4;
#pragma unroll
      for (int r = 0; r < 4; ++r)
        sm[(rl + r) * 136 + cl] = (short)f2bf(fmaxf(acc[mi][ni][r] + bv, 0.0f));
    }
  }
  __syncthreads();
  {
    int row = t >> 1, half = t & 1;
    const short* src = sm + row * 136 + half * 64;
    unsigned short* dst = C + (size_t)(m0 + row) * N + n0 + half * 64;
#pragma unroll
    for (int i = 0; i < 8; ++i)
      *(s16x8*)(dst + i * 8) = *(const s16x8*)(src + i * 8);
  }
}

// ---------------------------------------------------------------- fc2 fused with logits: atomicAdd partial dots
__global__ __launch_bounds__(256) void k_fc2log(const unsigned short* __restrict__ A,
                                                const unsigned short* __restrict__ Bt,
                                                const float* __restrict__ bias,
                                                const float* __restrict__ w3,
                                                float* __restrict__ logits,
                                                int base) {
  __shared__ __align__(16) short sm[16384];
  int t = threadIdx.x, lane = t & 63, w = t >> 6;
  int wm = w & 1, wn = w >> 1;
  int lr = lane & 15, ls = lane >> 4;
  int m0 = blockIdx.x * 128, n0 = blockIdx.y * 128;

  f32x4 acc[4][4];
#pragma unroll
  for (int i = 0; i < 4; ++i)
#pragma unroll
    for (int j = 0; j < 4; ++j) acc[i][j] = (f32x4){0.f, 0.f, 0.f, 0.f};

  fc_kloop(A, Bt, sm, m0, n0, acc);

  // epilogue: psum[mi][r] = sum over this wave's 64 cols of relu(acc+b2)*w3
  float psum[4][4];
#pragma unroll
  for (int mi = 0; mi < 4; ++mi)
#pragma unroll
    for (int r = 0; r < 4; ++r) psum[mi][r] = 0.0f;
#pragma unroll
  for (int ni = 0; ni < 4; ++ni) {
    int col = n0 + wn * 64 + ni * 16 + lr;
    float bv = bias[col];
    float wv = w3[col];
#pragma unroll
    for (int mi = 0; mi < 4; ++mi)
#pragma unroll
      for (int r = 0; r < 4; ++r)
        psum[mi][r] += fmaxf(acc[mi][ni][r] + bv, 0.0f) * wv;
  }
#pragma unroll
  for (int mi = 0; mi < 4; ++mi)
#pragma unroll
    for (int r = 0; r < 4; ++r) {
      float v = psum[mi][r];
      v += __shfl_xor(v, 1, 64);
      v += __shfl_xor(v, 2, 64);
      v += __shfl_xor(v, 4, 64);
      v += __shfl_xor(v, 8, 64);
      if (lr == 0) {
        int row = m0 + wm * 64 + mi * 16 + ls * 4 + r;
        atomicAdd(&logits[base + row], v);
      }
    }
}

// ---------------------------------------------------------------- final: sigmoid + keep
__global__ __launch_bounds__(256) void k_fin(const float* __restrict__ logits,
                                             const float* __restrict__ b3,
                                             const int* __restrict__ iskeep,
                                             float* __restrict__ oscore,
                                             float* __restrict__ okeep,
                                             int base) {
  int gl = base + blockIdx.x * 256 + threadIdx.x;
  float sc = sigm(logits[gl] + b3[0]);
  oscore[gl] = sc;
  okeep[gl] = (iskeep[gl] && sc > 0.05f) ? 1.0f : 0.0f;
}

// ================================================================ host
extern "C" void kernel_launch(void* const* d_in, const int* in_sizes, int n_in,
                              void* d_out, int out_size, void* d_ws, size_t ws_size,
                              hipStream_t stream) {
  const float* output     = (const float*)d_in[0];
  const float* features   = (const float*)d_in[1];
  const float* line_preds = (const float*)d_in[2];
  const float* conv_w     = (const float*)d_in[3];
  const float* conv_b     = (const float*)d_in[4];
  const float* w1         = (const float*)d_in[5];
  const float* b1         = (const float*)d_in[6];
  const float* w2         = (const float*)d_in[7];
  const float* b2         = (const float*)d_in[8];
  const float* w3         = (const float*)d_in[9];
  const float* b3         = (const float*)d_in[10];

  char* ws = (char*)d_ws;
  size_t off = 0;
  auto alloc = [&](size_t bytes) -> void* {
    void* p = ws + off;
    off += (bytes + 255) & ~(size_t)255;
    return p;
  };
  float* wt      = (float*)alloc((size_t)256 * 128 * 4);
  unsigned short* loi = (unsigned short*)alloc((size_t)NB * HW * 128 * 2);
  float* jloc    = (float*)alloc((size_t)NB * HW * 4);
  unsigned long long* keys = (unsigned long long*)alloc((size_t)NB * HW * 8);
  float* jx      = (float*)alloc((size_t)NB * NTOPK * 4);
  float* jy      = (float*)alloc((size_t)NB * NTOPK * 4);
  float4* lines4 = (float4*)alloc((size_t)NB * HW * 16);
  int* iskeep    = (int*)alloc((size_t)NB * HW * 4);
  float* logits  = (float*)alloc((size_t)NB * HW * 4);
  unsigned short* w1b = (unsigned short*)alloc((size_t)1024 * 1024 * 2);   // [N][K] bf16
  unsigned short* w2b = (unsigned short*)alloc((size_t)1024 * 1024 * 2);
  size_t fixed = off;

  // pick activation size: merged (both images, M=32768) if it fits, else per-image chunks
  bool merged = (fixed + (size_t)2 * NB * HW * 1024 * 2 + 512 <= ws_size);
  int CH = 128;
  if (!merged) {
    const int cands[8] = {16384, 8192, 4096, 2048, 1024, 512, 256, 128};
    for (int ci = 0; ci < 8; ++ci) {
      if (fixed + (size_t)2 * cands[ci] * 1024 * 2 + 512 <= ws_size) { CH = cands[ci]; break; }
    }
  }
  size_t actrows = merged ? (size_t)NB * HW : (size_t)CH;
  unsigned short* xvec = (unsigned short*)alloc(actrows * 1024 * 2);
  unsigned short* h1   = (unsigned short*)alloc(actrows * 1024 * 2);

  float* out_lines  = (float*)d_out;              // (B, L, 2, 2)
  float* out_scores = out_lines + (size_t)NB * HW * 4;
  float* out_keep   = out_scores + (size_t)NB * HW;

  k_transpose_w<<<128, 256, 0, stream>>>(conv_w, wt);
  k_wtrans<<<dim3(32, 32), 256, 0, stream>>>(w1, w1b);
  k_wtrans<<<dim3(32, 32), 256, 0, stream>>>(w2, w2b);
  k_loi<<<dim3(HW / 64, NB), 256, 0, stream>>>(features, wt, conv_b, loi);
  k_jloc<<<NB * HW / 256, 256, 0, stream>>>(output, jloc);
  k_nmskey<<<NB * HW / 256, 256, 0, stream>>>(jloc, keys);
  k_topk<<<NB, 1024, 0, stream>>>(keys, output, jx, jy);
  k_lines<<<dim3(HW / 256, NB), 256, 0, stream>>>(line_preds, jx, jy, lines4, iskeep, out_lines, logits);

  if (merged) {
    for (int b = 0; b < NB; ++b)
      k_sample<<<HW / 2, 128, 0, stream>>>(loi, lines4, xvec + (size_t)b * HW * 1024, b, 0);
    int M = NB * HW;
    k_fc1<<<dim3(M / 128, 8), 256, 0, stream>>>(xvec, w1b, b1, h1);
    k_fc2log<<<dim3(M / 128, 8), 256, 0, stream>>>(h1, w2b, b2, w3, logits, 0);
    k_fin<<<M / 256, 256, 0, stream>>>(logits, b3, iskeep, out_scores, out_keep, 0);
  } else {
    int nchunk = HW / CH;
    for (int b = 0; b < NB; ++b) {
      for (int ci = 0; ci < nchunk; ++ci) {
        int l0 = ci * CH;
        int base = b * HW + l0;
        k_sample<<<CH / 2, 128, 0, stream>>>(loi, lines4, xvec, b, l0);
        k_fc1<<<dim3(CH / 128, 8), 256, 0, stream>>>(xvec, w1b, b1, h1);
        k_fc2log<<<dim3(CH / 128, 8), 256, 0, stream>>>(h1, w2b, b2, w3, logits, base);
        k_fin<<<CH / 256, 256, 0, stream>>>(logits, b3, iskeep, out_scores, out_keep, base);
      }
    }
  }
}

// Round 6
// 516.642 us; speedup vs baseline: 1.0748x; 1.0748x over previous
//
#include <hip/hip_runtime.h>
#include <hip/hip_bf16.h>
#include <cstdint>
#include <cstddef>

#define HW     16384      // H*W
#define WIDTH  128
#define NB     2
#define NTOPK  300
#define JUNC_TH 0.008f

typedef __attribute__((ext_vector_type(8))) short s16x8;
typedef __attribute__((ext_vector_type(4))) float f32x4;

// ---------------------------------------------------------------- utilities
__device__ __forceinline__ float sigm(float x) { return 1.0f / (1.0f + expf(-x)); }

__device__ __forceinline__ unsigned short f2bf(float f) {
  __hip_bfloat16 h = __float2bfloat16(f);
  return __hip_bfloat16_raw(h).x;
}
__device__ __forceinline__ float bf2f(unsigned short u) {
  __hip_bfloat16_raw r; r.x = u;
  return __bfloat162float(__hip_bfloat16(r));
}
__device__ __forceinline__ float2 bf2x2(unsigned int u) {
  return make_float2(__uint_as_float(u << 16), __uint_as_float(u & 0xffff0000u));
}

#define GLOAD_LDS16(gp, lp)                                                        \
  __builtin_amdgcn_global_load_lds((const __attribute__((address_space(1))) void*)(gp), \
                                   (__attribute__((address_space(3))) void*)(lp), 16, 0, 0)

// ---------------------------------------------------------------- W transpose (256x128 <- 128x256), fp32
__global__ void k_transpose_w(const float* __restrict__ w, float* __restrict__ wt) {
  int i = blockIdx.x * 256 + threadIdx.x;   // 32768
  int d = i & 127, c = i >> 7;
  wt[c * 128 + d] = w[d * 256 + c];
}

// ---------------------------------------------------------------- FC weight transpose+cast: wt_bf16[n][k] = w[k][n]
__global__ __launch_bounds__(256) void k_wtrans(const float* __restrict__ w,
                                                unsigned short* __restrict__ wt) {
  __shared__ float tile[32][33];
  int n0 = blockIdx.x * 32, k0 = blockIdx.y * 32;
  int tx = threadIdx.x & 31, ty = threadIdx.x >> 5;   // 32 x 8
#pragma unroll
  for (int r = 0; r < 32; r += 8)
    tile[ty + r][tx] = w[(size_t)(k0 + ty + r) * 1024 + n0 + tx];
  __syncthreads();
#pragma unroll
  for (int r = 0; r < 32; r += 8)
    wt[(size_t)(n0 + ty + r) * 1024 + k0 + tx] = f2bf(tile[tx][ty + r]);
}

// ---------------------------------------------------------------- loi GEMM (fp32 math, bf16 store): loi_t[b][p][d]
__global__ __launch_bounds__(256) void k_loi(const float* __restrict__ F,
                                             const float* __restrict__ wt,
                                             const float* __restrict__ bias,
                                             unsigned short* __restrict__ loi) {
  int b = blockIdx.y;
  int p0 = blockIdx.x * 64;
  __shared__ float As[8][64];
  __shared__ float Bs[8][128];
  int t = threadIdx.x;
  int tn = t & 15;    // n group: n = tn*8
  int tm = t >> 4;    // m group: m = tm*4
  float acc[4][8];
#pragma unroll
  for (int i = 0; i < 4; ++i)
#pragma unroll
    for (int j = 0; j < 8; ++j) acc[i][j] = 0.0f;

  const float* Fb = F + (size_t)b * 256 * HW;
  for (int c0 = 0; c0 < 256; c0 += 8) {
    __syncthreads();
    if (t < 128) {
      int kk = t >> 4, mv = t & 15;
      float4 v = *(const float4*)(Fb + (size_t)(c0 + kk) * HW + p0 + mv * 4);
      *(float4*)&As[kk][mv * 4] = v;
    }
    {
      int kk = t >> 5, dv = t & 31;
      float4 v = *(const float4*)(wt + (size_t)(c0 + kk) * 128 + dv * 4);
      *(float4*)&Bs[kk][dv * 4] = v;
    }
    __syncthreads();
#pragma unroll
    for (int kk = 0; kk < 8; ++kk) {
      float4 a4 = *(const float4*)&As[kk][tm * 4];
      float4 b0 = *(const float4*)&Bs[kk][tn * 8];
      float4 b1 = *(const float4*)&Bs[kk][tn * 8 + 4];
      float av[4] = {a4.x, a4.y, a4.z, a4.w};
      float bv[8] = {b0.x, b0.y, b0.z, b0.w, b1.x, b1.y, b1.z, b1.w};
#pragma unroll
      for (int i = 0; i < 4; ++i)
#pragma unroll
        for (int j = 0; j < 8; ++j) acc[i][j] += av[i] * bv[j];
    }
  }
  float4 c0v = *(const float4*)(bias + tn * 8);
  float4 c1v = *(const float4*)(bias + tn * 8 + 4);
  float bb[8] = {c0v.x, c0v.y, c0v.z, c0v.w, c1v.x, c1v.y, c1v.z, c1v.w};
#pragma unroll
  for (int i = 0; i < 4; ++i) {
    int p = p0 + tm * 4 + i;
    alignas(16) unsigned short o[8];
#pragma unroll
    for (int j = 0; j < 8; ++j) o[j] = f2bf(acc[i][j] + bb[j]);
    *(s16x8*)(loi + ((size_t)b * HW + p) * 128 + tn * 8) = *(const s16x8*)o;
  }
}

// ---------------------------------------------------------------- jloc = softmax(out9[5:7])[1]
__global__ void k_jloc(const float* __restrict__ out9, float* __restrict__ jloc) {
  int i = blockIdx.x * 256 + threadIdx.x;    // NB*HW
  int b = i >> 14, p = i & (HW - 1);
  const float* base = out9 + (size_t)b * 9 * HW;
  float o5 = base[5 * HW + p], o6 = base[6 * HW + p];
  float m = fmaxf(o5, o6);
  float e5 = expf(o5 - m), e6 = expf(o6 - m);
  jloc[i] = e6 / (e5 + e6);
}

// ---------------------------------------------------------------- NMS + sortable key
__global__ void k_nmskey(const float* __restrict__ jloc, unsigned long long* __restrict__ keys) {
  int i = blockIdx.x * 256 + threadIdx.x;
  int b = i >> 14, p = i & (HW - 1);
  int y = p >> 7, x = p & 127;
  const float* J = jloc + (size_t)b * HW;
  float c = J[p];
  float m = c;
  for (int dy = -1; dy <= 1; ++dy) {
    int yy = y + dy;
    if (yy < 0 || yy > 127) continue;
    for (int dx = -1; dx <= 1; ++dx) {
      int xx = x + dx;
      if (xx < 0 || xx > 127) continue;
      m = fmaxf(m, J[yy * WIDTH + xx]);
    }
  }
  unsigned int vb = (c == m) ? __float_as_uint(c) : 0u;   // jloc > 0 always -> bits monotone
  keys[i] = ((unsigned long long)vb << 32) | (unsigned int)(~p);
}

// ---------------------------------------------------------------- top-300 per image via bitonic sort (1 block/image)
__global__ __launch_bounds__(1024) void k_topk(const unsigned long long* __restrict__ keys,
                                               const float* __restrict__ out9,
                                               float* __restrict__ jx, float* __restrict__ jy) {
  int b = blockIdx.x;
  __shared__ unsigned long long cand[4096];
  __shared__ int cnt;
  int t = threadIdx.x;
  if (t == 0) cnt = 0;
#pragma unroll
  for (int i = t; i < 4096; i += 1024) cand[i] = 0ull;
  __syncthreads();
  const unsigned long long* K = keys + (size_t)b * HW;
  for (int i = t; i < HW; i += 1024) {
    unsigned long long k = K[i];
    if ((k >> 32) != 0ull) {
      int pos = atomicAdd(&cnt, 1);
      if (pos < 4096) cand[pos] = k;
    }
  }
  __syncthreads();
  // bitonic sort, descending (keys distinct except zero-padding)
  for (int k = 2; k <= 4096; k <<= 1) {
    for (int j = k >> 1; j > 0; j >>= 1) {
#pragma unroll
      for (int idx = t; idx < 4096; idx += 1024) {
        int ixj = idx ^ j;
        if (ixj > idx) {
          unsigned long long a = cand[idx], c = cand[ixj];
          bool up = ((idx & k) == 0);
          if (up ? (a < c) : (a > c)) { cand[idx] = c; cand[ixj] = a; }
        }
      }
      __syncthreads();
    }
  }
  if (t < NTOPK) {
    const float* o7 = out9 + (size_t)b * 9 * HW + 7 * HW;
    const float* o8 = out9 + (size_t)b * 9 * HW + 8 * HW;
    unsigned long long bb = cand[t];
    unsigned int vb = (unsigned int)(bb >> 32);
    float val = __uint_as_float(vb);
    if (vb != 0u && val > JUNC_TH) {
      int p = (int)(~((unsigned int)(bb & 0xffffffffull))) & (HW - 1);
      float ox = sigm(o7[p]) - 0.5f;
      float oy = sigm(o8[p]) - 0.5f;
      jx[b * NTOPK + t] = (float)(p & 127) + ox + 0.5f;
      jy[b * NTOPK + t] = (float)(p >> 7) + oy + 0.5f;
    } else {
      jx[b * NTOPK + t] = 1000000.0f;
      jy[b * NTOPK + t] = 1000000.0f;
    }
  }
}

// ---------------------------------------------------------------- per-line argmin assignment + lines2 output (+ logits zero)
__global__ __launch_bounds__(256) void k_lines(const float* __restrict__ lp,
                                               const float* __restrict__ jx,
                                               const float* __restrict__ jy,
                                               float4* __restrict__ lines4,
                                               int* __restrict__ iskeep,
                                               float* __restrict__ out_lines,
                                               float* __restrict__ logits) {
  int b = blockIdx.y;
  int l = blockIdx.x * 256 + threadIdx.x;
  __shared__ float jxs[NTOPK], jys[NTOPK];
  for (int i = threadIdx.x; i < NTOPK; i += 256) {
    jxs[i] = jx[b * NTOPK + i];
    jys[i] = jy[b * NTOPK + i];
  }
  __syncthreads();
  int gl = b * HW + l;
  const float* L = lp + (size_t)gl * 4;
  float x1 = L[0], y1 = L[1], x2 = L[2], y2 = L[3];
  float bd1 = 3.4e38f, bd2 = 3.4e38f;
  int i1 = 0, i2 = 0;
  for (int j = 0; j < NTOPK; ++j) {
    float ax = __fsub_rn(x1, jxs[j]);
    float ay = __fsub_rn(y1, jys[j]);
    float d1 = __fadd_rn(__fmul_rn(ax, ax), __fmul_rn(ay, ay));
    if (d1 < bd1) { bd1 = d1; i1 = j; }
    float ex = __fsub_rn(x2, jxs[j]);
    float ey = __fsub_rn(y2, jys[j]);
    float d2 = __fadd_rn(__fmul_rn(ex, ex), __fmul_rn(ey, ey));
    if (d2 < bd2) { bd2 = d2; i2 = j; }
  }
  int imin = min(i1, i2), imax = max(i1, i2);
  float sx1 = jxs[imin], sy1 = jys[imin], sx2 = jxs[imax], sy2 = jys[imax];
  lines4[gl] = make_float4(sx1, sy1, sx2, sy2);
  iskeep[gl] = (imin < imax) ? 1 : 0;
  logits[gl] = 0.0f;
  ((float4*)out_lines)[gl] = make_float4(sx1 * 4.0f, sy1 * 4.0f, sx2 * 4.0f, sy2 * 4.0f);
}

// ---------------------------------------------------------------- bilinear sample + maxpool
// 2 lines per block, 128 threads: t>>6 = line-in-block, t&63 = channel pair.
__global__ __launch_bounds__(128) void k_sample(const unsigned short* __restrict__ loi,
                                                const float4* __restrict__ lines4,
                                                unsigned short* __restrict__ xvec,
                                                int b, int l0) {
  __shared__ int   soff[2][32][4];
  __shared__ float swt[2][32][4];
  int t = threadIdx.x;
  if (t < 64) {
    int li = t >> 5, k = t & 31;
    int l = l0 + blockIdx.x * 2 + li;
    float4 ln = lines4[b * HW + l];
    float tt = (float)k * (1.0f / 31.0f);
    float tc = 1.0f - tt;
    float px = ln.x * tt + ln.z * tc - 0.5f;
    float py = ln.y * tt + ln.w * tc - 0.5f;
    float px0 = fminf(fmaxf(floorf(px), 0.0f), 127.0f);
    float py0 = fminf(fmaxf(floorf(py), 0.0f), 127.0f);
    float px1 = fminf(px0 + 1.0f, 127.0f);
    float py1 = fminf(py0 + 1.0f, 127.0f);
    int ix0 = (int)px0, iy0 = (int)py0, ix1 = (int)px1, iy1 = (int)py1;
    float wy1 = __fsub_rn(py1, py), wy0 = __fsub_rn(py, py0);
    float wx1 = __fsub_rn(px1, px), wx0 = __fsub_rn(px, px0);
    soff[li][k][0] = (iy0 * WIDTH + ix0) * 128;
    soff[li][k][1] = (iy1 * WIDTH + ix0) * 128;
    soff[li][k][2] = (iy0 * WIDTH + ix1) * 128;
    soff[li][k][3] = (iy1 * WIDTH + ix1) * 128;
    swt[li][k][0] = __fmul_rn(wy1, wx1);   // wa -> r00
    swt[li][k][1] = __fmul_rn(wy0, wx1);   // wb -> r10
    swt[li][k][2] = __fmul_rn(wy1, wx0);   // wc -> r01
    swt[li][k][3] = __fmul_rn(wy0, wx0);   // wd -> r11
  }
  __syncthreads();
  int li = t >> 6, c2 = t & 63;            // channels 2*c2, 2*c2+1
  int l = l0 + blockIdx.x * 2 + li;
  const unsigned short* Lb = loi + (size_t)b * HW * 128 + (c2 << 1);
  float rm0 = -3.4e38f, rm1 = -3.4e38f;
  alignas(16) unsigned short outv[16];
#pragma unroll 4
  for (int k = 0; k < 32; ++k) {
    int4   o = *(const int4*)soff[li][k];
    float4 w = *(const float4*)swt[li][k];
    unsigned int u0 = *(const unsigned int*)(Lb + o.x);
    unsigned int u1 = *(const unsigned int*)(Lb + o.y);
    unsigned int u2 = *(const unsigned int*)(Lb + o.z);
    unsigned int u3 = *(const unsigned int*)(Lb + o.w);
    float2 v0 = bf2x2(u0), v1 = bf2x2(u1), v2 = bf2x2(u2), v3 = bf2x2(u3);
    float a0 = __fadd_rn(__fadd_rn(__fadd_rn(__fmul_rn(v0.x, w.x), __fmul_rn(v1.x, w.y)),
                                   __fmul_rn(v2.x, w.z)), __fmul_rn(v3.x, w.w));
    float a1 = __fadd_rn(__fadd_rn(__fadd_rn(__fmul_rn(v0.y, w.x), __fmul_rn(v1.y, w.y)),
                                   __fmul_rn(v2.y, w.z)), __fmul_rn(v3.y, w.w));
    rm0 = fmaxf(rm0, a0);
    rm1 = fmaxf(rm1, a1);
    if ((k & 3) == 3) {
      outv[k >> 2]       = f2bf(rm0);
      outv[8 + (k >> 2)] = f2bf(rm1);
      rm0 = -3.4e38f; rm1 = -3.4e38f;
    }
  }
  unsigned short* dst = xvec + (size_t)(l - l0) * 1024 + c2 * 16;
  *(s16x8*)dst       = *(const s16x8*)outv;
  *(s16x8*)(dst + 8) = *(const s16x8*)(outv + 8);
}

// ---------------------------------------------------------------- shared FC K-loop: BM=256, BN=128, BK=32, 512 threads / 8 waves
// global_load_lds staging, double-buffered LDS, 1 barrier/iter.
// Wave w: wm = w&3 (m 64-slice), wn = w>>2 (n 64-slice). Per buffer: A 16 tiles
// of 512 shorts (16 rows x 32 k), B 8 tiles. Buffer = 12288 shorts (24 KB).
__device__ __forceinline__ void fc_kloop(const unsigned short* __restrict__ A,
                                         const unsigned short* __restrict__ Bt,
                                         short* sm, int m0, int n0,
                                         f32x4 acc[4][4]) {
  const int K = 1024;
  int t = threadIdx.x, lane = t & 63, w = t >> 6;   // w 0..7
  int wm = w & 3, wn = w >> 2;
  int lr = lane & 15, ls = lane >> 4;

  const unsigned short* gA0 = A + (size_t)(m0 + w * 16 + lr) * K + ls * 8;
  const unsigned short* gA1 = A + (size_t)(m0 + (w + 8) * 16 + lr) * K + ls * 8;
  const unsigned short* gB  = Bt + (size_t)(n0 + w * 16 + lr) * K + ls * 8;
  int oA0 = w * 512 + lane * 8;
  int oA1 = (w + 8) * 512 + lane * 8;
  int oB  = 8192 + w * 512 + lane * 8;

  GLOAD_LDS16(gA0, sm + oA0);
  GLOAD_LDS16(gA1, sm + oA1);
  GLOAD_LDS16(gB,  sm + oB);
  __syncthreads();

  int cur = 0;
  for (int k0 = 0; k0 < K; k0 += 32) {
    int nxt = cur ^ 1;
    if (k0 + 32 < K) {
      int ko = k0 + 32;
      short* d = sm + nxt * 12288;
      GLOAD_LDS16(gA0 + ko, d + oA0);
      GLOAD_LDS16(gA1 + ko, d + oA1);
      GLOAD_LDS16(gB  + ko, d + oB);
    }
    const short* As = sm + cur * 12288;
    const short* Bs = As + 8192;
    s16x8 af[4], bfr[4];
#pragma unroll
    for (int mi = 0; mi < 4; ++mi) af[mi] = *(const s16x8*)(As + (wm * 4 + mi) * 512 + lane * 8);
#pragma unroll
    for (int ni = 0; ni < 4; ++ni) bfr[ni] = *(const s16x8*)(Bs + (wn * 4 + ni) * 512 + lane * 8);
#pragma unroll
    for (int mi = 0; mi < 4; ++mi)
#pragma unroll
      for (int ni = 0; ni < 4; ++ni)
        acc[mi][ni] = __builtin_amdgcn_mfma_f32_16x16x32_bf16(af[mi], bfr[ni], acc[mi][ni], 0, 0, 0);
    __syncthreads();
    cur = nxt;
  }
}

// ---------------------------------------------------------------- fc1: C = relu(A @ Bt^T + bias), bf16 out, 256x128 tile
__global__ __launch_bounds__(512) void k_fc1(const unsigned short* __restrict__ A,
                                             const unsigned short* __restrict__ Bt,
                                             const float* __restrict__ bias,
                                             unsigned short* __restrict__ C) {
  const int N = 1024;
  __shared__ __align__(16) short sm[24576];   // loop: 2x12288; epilogue pass: 128x136=17408
  int t = threadIdx.x, lane = t & 63, w = t >> 6;
  int wm = w & 3, wn = w >> 2;
  int lr = lane & 15, ls = lane >> 4;
  int m0 = blockIdx.x * 256, n0 = blockIdx.y * 128;

  f32x4 acc[4][4];
#pragma unroll
  for (int i = 0; i < 4; ++i)
#pragma unroll
    for (int j = 0; j < 4; ++j) acc[i][j] = (f32x4){0.f, 0.f, 0.f, 0.f};

  fc_kloop(A, Bt, sm, m0, n0, acc);
  __syncthreads();

  // two-pass LDS-staged epilogue (128 rows per pass), coalesced stores
  for (int p = 0; p < 2; ++p) {
    if ((wm >> 1) == p) {
#pragma unroll
      for (int ni = 0; ni < 4; ++ni) {
        int cl = wn * 64 + ni * 16 + lr;
        float bv = bias[n0 + cl];
#pragma unroll
        for (int mi = 0; mi < 4; ++mi) {
          int rl = (wm & 1) * 64 + mi * 16 + ls * 4;
#pragma unroll
          for (int r = 0; r < 4; ++r)
            sm[(rl + r) * 136 + cl] = (short)f2bf(fmaxf(acc[mi][ni][r] + bv, 0.0f));
        }
      }
    }
    __syncthreads();
    {
      int row = t >> 2, q = t & 3;
      const short* src = sm + row * 136 + q * 32;
      unsigned short* dst = C + (size_t)(m0 + p * 128 + row) * N + n0 + q * 32;
#pragma unroll
      for (int i = 0; i < 4; ++i)
        *(s16x8*)(dst + i * 8) = *(const s16x8*)(src + i * 8);
    }
    __syncthreads();
  }
}

// ---------------------------------------------------------------- fc2 fused with logits: atomicAdd partial dots, 256x128 tile
__global__ __launch_bounds__(512) void k_fc2log(const unsigned short* __restrict__ A,
                                                const unsigned short* __restrict__ Bt,
                                                const float* __restrict__ bias,
                                                const float* __restrict__ w3,
                                                float* __restrict__ logits,
                                                int base) {
  __shared__ __align__(16) short sm[24576];
  int t = threadIdx.x, lane = t & 63, w = t >> 6;
  int wm = w & 3, wn = w >> 2;
  int lr = lane & 15, ls = lane >> 4;
  int m0 = blockIdx.x * 256, n0 = blockIdx.y * 128;

  f32x4 acc[4][4];
#pragma unroll
  for (int i = 0; i < 4; ++i)
#pragma unroll
    for (int j = 0; j < 4; ++j) acc[i][j] = (f32x4){0.f, 0.f, 0.f, 0.f};

  fc_kloop(A, Bt, sm, m0, n0, acc);

  // epilogue: psum[mi][r] = sum over this wave's 64 cols of relu(acc+b2)*w3
  float psum[4][4];
#pragma unroll
  for (int mi = 0; mi < 4; ++mi)
#pragma unroll
    for (int r = 0; r < 4; ++r) psum[mi][r] = 0.0f;
#pragma unroll
  for (int ni = 0; ni < 4; ++ni) {
    int col = n0 + wn * 64 + ni * 16 + lr;
    float bv = bias[col];
    float wv = w3[col];
#pragma unroll
    for (int mi = 0; mi < 4; ++mi)
#pragma unroll
      for (int r = 0; r < 4; ++r)
        psum[mi][r] += fmaxf(acc[mi][ni][r] + bv, 0.0f) * wv;
  }
#pragma unroll
  for (int mi = 0; mi < 4; ++mi)
#pragma unroll
    for (int r = 0; r < 4; ++r) {
      float v = psum[mi][r];
      v += __shfl_xor(v, 1, 64);
      v += __shfl_xor(v, 2, 64);
      v += __shfl_xor(v, 4, 64);
      v += __shfl_xor(v, 8, 64);
      if (lr == 0) {
        int row = m0 + wm * 64 + mi * 16 + ls * 4 + r;
        atomicAdd(&logits[base + row], v);
      }
    }
}

// ---------------------------------------------------------------- final: sigmoid + keep
__global__ __launch_bounds__(256) void k_fin(const float* __restrict__ logits,
                                             const float* __restrict__ b3,
                                             const int* __restrict__ iskeep,
                                             float* __restrict__ oscore,
                                             float* __restrict__ okeep,
                                             int base) {
  int gl = base + blockIdx.x * 256 + threadIdx.x;
  float sc = sigm(logits[gl] + b3[0]);
  oscore[gl] = sc;
  okeep[gl] = (iskeep[gl] && sc > 0.05f) ? 1.0f : 0.0f;
}

// ================================================================ host
extern "C" void kernel_launch(void* const* d_in, const int* in_sizes, int n_in,
                              void* d_out, int out_size, void* d_ws, size_t ws_size,
                              hipStream_t stream) {
  const float* output     = (const float*)d_in[0];
  const float* features   = (const float*)d_in[1];
  const float* line_preds = (const float*)d_in[2];
  const float* conv_w     = (const float*)d_in[3];
  const float* conv_b     = (const float*)d_in[4];
  const float* w1         = (const float*)d_in[5];
  const float* b1         = (const float*)d_in[6];
  const float* w2         = (const float*)d_in[7];
  const float* b2         = (const float*)d_in[8];
  const float* w3         = (const float*)d_in[9];
  const float* b3         = (const float*)d_in[10];

  char* ws = (char*)d_ws;
  size_t off = 0;
  auto alloc = [&](size_t bytes) -> void* {
    void* p = ws + off;
    off += (bytes + 255) & ~(size_t)255;
    return p;
  };
  float* wt      = (float*)alloc((size_t)256 * 128 * 4);
  unsigned short* loi = (unsigned short*)alloc((size_t)NB * HW * 128 * 2);
  float* jloc    = (float*)alloc((size_t)NB * HW * 4);
  unsigned long long* keys = (unsigned long long*)alloc((size_t)NB * HW * 8);
  float* jx      = (float*)alloc((size_t)NB * NTOPK * 4);
  float* jy      = (float*)alloc((size_t)NB * NTOPK * 4);
  float4* lines4 = (float4*)alloc((size_t)NB * HW * 16);
  int* iskeep    = (int*)alloc((size_t)NB * HW * 4);
  float* logits  = (float*)alloc((size_t)NB * HW * 4);
  unsigned short* w1b = (unsigned short*)alloc((size_t)1024 * 1024 * 2);   // [N][K] bf16
  unsigned short* w2b = (unsigned short*)alloc((size_t)1024 * 1024 * 2);
  size_t fixed = off;

  // pick activation size: merged (both images, M=32768) if it fits, else per-image chunks
  bool merged = (fixed + (size_t)2 * NB * HW * 1024 * 2 + 512 <= ws_size);
  int CH = 256;
  if (!merged) {
    const int cands[7] = {16384, 8192, 4096, 2048, 1024, 512, 256};
    for (int ci = 0; ci < 7; ++ci) {
      if (fixed + (size_t)2 * cands[ci] * 1024 * 2 + 512 <= ws_size) { CH = cands[ci]; break; }
    }
  }
  size_t actrows = merged ? (size_t)NB * HW : (size_t)CH;
  unsigned short* xvec = (unsigned short*)alloc(actrows * 1024 * 2);
  unsigned short* h1   = (unsigned short*)alloc(actrows * 1024 * 2);

  float* out_lines  = (float*)d_out;              // (B, L, 2, 2)
  float* out_scores = out_lines + (size_t)NB * HW * 4;
  float* out_keep   = out_scores + (size_t)NB * HW;

  k_transpose_w<<<128, 256, 0, stream>>>(conv_w, wt);
  k_wtrans<<<dim3(32, 32), 256, 0, stream>>>(w1, w1b);
  k_wtrans<<<dim3(32, 32), 256, 0, stream>>>(w2, w2b);
  k_loi<<<dim3(HW / 64, NB), 256, 0, stream>>>(features, wt, conv_b, loi);
  k_jloc<<<NB * HW / 256, 256, 0, stream>>>(output, jloc);
  k_nmskey<<<NB * HW / 256, 256, 0, stream>>>(jloc, keys);
  k_topk<<<NB, 1024, 0, stream>>>(keys, output, jx, jy);
  k_lines<<<dim3(HW / 256, NB), 256, 0, stream>>>(line_preds, jx, jy, lines4, iskeep, out_lines, logits);

  if (merged) {
    for (int b = 0; b < NB; ++b)
      k_sample<<<HW / 2, 128, 0, stream>>>(loi, lines4, xvec + (size_t)b * HW * 1024, b, 0);
    int M = NB * HW;
    k_fc1<<<dim3(M / 256, 8), 512, 0, stream>>>(xvec, w1b, b1, h1);
    k_fc2log<<<dim3(M / 256, 8), 512, 0, stream>>>(h1, w2b, b2, w3, logits, 0);
    k_fin<<<M / 256, 256, 0, stream>>>(logits, b3, iskeep, out_scores, out_keep, 0);
  } else {
    int nchunk = HW / CH;
    for (int b = 0; b < NB; ++b) {
      for (int ci = 0; ci < nchunk; ++ci) {
        int l0 = ci * CH;
        int base = b * HW + l0;
        k_sample<<<CH / 2, 128, 0, stream>>>(loi, lines4, xvec, b, l0);
        k_fc1<<<dim3(CH / 256, 8), 512, 0, stream>>>(xvec, w1b, b1, h1);
        k_fc2log<<<dim3(CH / 256, 8), 512, 0, stream>>>(h1, w2b, b2, w3, logits, base);
        k_fin<<<CH / 256, 256, 0, stream>>>(logits, b3, iskeep, out_scores, out_keep, base);
      }
    }
  }
}

// Round 7
// 507.797 us; speedup vs baseline: 1.0935x; 1.0174x over previous
//
#include <hip/hip_runtime.h>
#include <hip/hip_bf16.h>
#include <cstdint>
#include <cstddef>

#define HW     16384      // H*W
#define WIDTH  128
#define NB     2
#define NTOPK  300
#define JUNC_TH 0.008f

typedef __attribute__((ext_vector_type(8))) short s16x8;
typedef __attribute__((ext_vector_type(4))) float f32x4;

// ---------------------------------------------------------------- utilities
__device__ __forceinline__ float sigm(float x) { return 1.0f / (1.0f + expf(-x)); }

__device__ __forceinline__ unsigned short f2bf(float f) {
  __hip_bfloat16 h = __float2bfloat16(f);
  return __hip_bfloat16_raw(h).x;
}
__device__ __forceinline__ float bf2f(unsigned short u) {
  __hip_bfloat16_raw r; r.x = u;
  return __bfloat162float(__hip_bfloat16(r));
}
__device__ __forceinline__ float2 bf2x2(unsigned int u) {
  return make_float2(__uint_as_float(u << 16), __uint_as_float(u & 0xffff0000u));
}

#define GLOAD_LDS16(gp, lp)                                                        \
  __builtin_amdgcn_global_load_lds((const __attribute__((address_space(1))) void*)(gp), \
                                   (__attribute__((address_space(3))) void*)(lp), 16, 0, 0)

// XCD-cohort swizzle: consecutive blocks round-robin across 8 XCDs (heuristic),
// so give each XCD a run of n-slices over ONE m-tile -> A-tile L2 reuse.
__device__ __forceinline__ void fc_tile_map(int bid, int nm, int& m_idx, int& n_idx) {
  if ((nm & 7) == 0) {
    int x = bid & 7;
    int k = bid >> 3;
    m_idx = x * (nm >> 3) + (k >> 3);
    n_idx = k & 7;
  } else {
    m_idx = bid >> 3;
    n_idx = bid & 7;
  }
}

// ---------------------------------------------------------------- W transpose (256x128 <- 128x256), fp32
__global__ void k_transpose_w(const float* __restrict__ w, float* __restrict__ wt) {
  int i = blockIdx.x * 256 + threadIdx.x;   // 32768
  int d = i & 127, c = i >> 7;
  wt[c * 128 + d] = w[d * 256 + c];
}

// ---------------------------------------------------------------- FC weight transpose+cast: wt_bf16[n][k] = w[k][n]
__global__ __launch_bounds__(256) void k_wtrans(const float* __restrict__ w,
                                                unsigned short* __restrict__ wt) {
  __shared__ float tile[32][33];
  int n0 = blockIdx.x * 32, k0 = blockIdx.y * 32;
  int tx = threadIdx.x & 31, ty = threadIdx.x >> 5;   // 32 x 8
#pragma unroll
  for (int r = 0; r < 32; r += 8)
    tile[ty + r][tx] = w[(size_t)(k0 + ty + r) * 1024 + n0 + tx];
  __syncthreads();
#pragma unroll
  for (int r = 0; r < 32; r += 8)
    wt[(size_t)(n0 + ty + r) * 1024 + k0 + tx] = f2bf(tile[tx][ty + r]);
}

// ---------------------------------------------------------------- loi GEMM (fp32 math, bf16 store): loi_t[b][p][d]
__global__ __launch_bounds__(256) void k_loi(const float* __restrict__ F,
                                             const float* __restrict__ wt,
                                             const float* __restrict__ bias,
                                             unsigned short* __restrict__ loi) {
  int b = blockIdx.y;
  int p0 = blockIdx.x * 64;
  __shared__ float As[8][64];
  __shared__ float Bs[8][128];
  int t = threadIdx.x;
  int tn = t & 15;    // n group: n = tn*8
  int tm = t >> 4;    // m group: m = tm*4
  float acc[4][8];
#pragma unroll
  for (int i = 0; i < 4; ++i)
#pragma unroll
    for (int j = 0; j < 8; ++j) acc[i][j] = 0.0f;

  const float* Fb = F + (size_t)b * 256 * HW;
  for (int c0 = 0; c0 < 256; c0 += 8) {
    __syncthreads();
    if (t < 128) {
      int kk = t >> 4, mv = t & 15;
      float4 v = *(const float4*)(Fb + (size_t)(c0 + kk) * HW + p0 + mv * 4);
      *(float4*)&As[kk][mv * 4] = v;
    }
    {
      int kk = t >> 5, dv = t & 31;
      float4 v = *(const float4*)(wt + (size_t)(c0 + kk) * 128 + dv * 4);
      *(float4*)&Bs[kk][dv * 4] = v;
    }
    __syncthreads();
#pragma unroll
    for (int kk = 0; kk < 8; ++kk) {
      float4 a4 = *(const float4*)&As[kk][tm * 4];
      float4 b0 = *(const float4*)&Bs[kk][tn * 8];
      float4 b1 = *(const float4*)&Bs[kk][tn * 8 + 4];
      float av[4] = {a4.x, a4.y, a4.z, a4.w};
      float bv[8] = {b0.x, b0.y, b0.z, b0.w, b1.x, b1.y, b1.z, b1.w};
#pragma unroll
      for (int i = 0; i < 4; ++i)
#pragma unroll
        for (int j = 0; j < 8; ++j) acc[i][j] += av[i] * bv[j];
    }
  }
  float4 c0v = *(const float4*)(bias + tn * 8);
  float4 c1v = *(const float4*)(bias + tn * 8 + 4);
  float bb[8] = {c0v.x, c0v.y, c0v.z, c0v.w, c1v.x, c1v.y, c1v.z, c1v.w};
#pragma unroll
  for (int i = 0; i < 4; ++i) {
    int p = p0 + tm * 4 + i;
    alignas(16) unsigned short o[8];
#pragma unroll
    for (int j = 0; j < 8; ++j) o[j] = f2bf(acc[i][j] + bb[j]);
    *(s16x8*)(loi + ((size_t)b * HW + p) * 128 + tn * 8) = *(const s16x8*)o;
  }
}

// ---------------------------------------------------------------- jloc = softmax(out9[5:7])[1]
__global__ void k_jloc(const float* __restrict__ out9, float* __restrict__ jloc) {
  int i = blockIdx.x * 256 + threadIdx.x;    // NB*HW
  int b = i >> 14, p = i & (HW - 1);
  const float* base = out9 + (size_t)b * 9 * HW;
  float o5 = base[5 * HW + p], o6 = base[6 * HW + p];
  float m = fmaxf(o5, o6);
  float e5 = expf(o5 - m), e6 = expf(o6 - m);
  jloc[i] = e6 / (e5 + e6);
}

// ---------------------------------------------------------------- NMS + sortable key
__global__ void k_nmskey(const float* __restrict__ jloc, unsigned long long* __restrict__ keys) {
  int i = blockIdx.x * 256 + threadIdx.x;
  int b = i >> 14, p = i & (HW - 1);
  int y = p >> 7, x = p & 127;
  const float* J = jloc + (size_t)b * HW;
  float c = J[p];
  float m = c;
  for (int dy = -1; dy <= 1; ++dy) {
    int yy = y + dy;
    if (yy < 0 || yy > 127) continue;
    for (int dx = -1; dx <= 1; ++dx) {
      int xx = x + dx;
      if (xx < 0 || xx > 127) continue;
      m = fmaxf(m, J[yy * WIDTH + xx]);
    }
  }
  unsigned int vb = (c == m) ? __float_as_uint(c) : 0u;   // jloc > 0 always -> bits monotone
  keys[i] = ((unsigned long long)vb << 32) | (unsigned int)(~p);
}

// ---------------------------------------------------------------- top-300 per image via bitonic sort (1 block/image)
__global__ __launch_bounds__(1024) void k_topk(const unsigned long long* __restrict__ keys,
                                               const float* __restrict__ out9,
                                               float* __restrict__ jx, float* __restrict__ jy) {
  int b = blockIdx.x;
  __shared__ unsigned long long cand[4096];
  __shared__ int cnt;
  int t = threadIdx.x;
  if (t == 0) cnt = 0;
#pragma unroll
  for (int i = t; i < 4096; i += 1024) cand[i] = 0ull;
  __syncthreads();
  const unsigned long long* K = keys + (size_t)b * HW;
  for (int i = t; i < HW; i += 1024) {
    unsigned long long k = K[i];
    if ((k >> 32) != 0ull) {
      int pos = atomicAdd(&cnt, 1);
      if (pos < 4096) cand[pos] = k;
    }
  }
  __syncthreads();
  // bitonic sort, descending (keys distinct except zero-padding)
  for (int k = 2; k <= 4096; k <<= 1) {
    for (int j = k >> 1; j > 0; j >>= 1) {
#pragma unroll
      for (int idx = t; idx < 4096; idx += 1024) {
        int ixj = idx ^ j;
        if (ixj > idx) {
          unsigned long long a = cand[idx], c = cand[ixj];
          bool up = ((idx & k) == 0);
          if (up ? (a < c) : (a > c)) { cand[idx] = c; cand[ixj] = a; }
        }
      }
      __syncthreads();
    }
  }
  if (t < NTOPK) {
    const float* o7 = out9 + (size_t)b * 9 * HW + 7 * HW;
    const float* o8 = out9 + (size_t)b * 9 * HW + 8 * HW;
    unsigned long long bb = cand[t];
    unsigned int vb = (unsigned int)(bb >> 32);
    float val = __uint_as_float(vb);
    if (vb != 0u && val > JUNC_TH) {
      int p = (int)(~((unsigned int)(bb & 0xffffffffull))) & (HW - 1);
      float ox = sigm(o7[p]) - 0.5f;
      float oy = sigm(o8[p]) - 0.5f;
      jx[b * NTOPK + t] = (float)(p & 127) + ox + 0.5f;
      jy[b * NTOPK + t] = (float)(p >> 7) + oy + 0.5f;
    } else {
      jx[b * NTOPK + t] = 1000000.0f;
      jy[b * NTOPK + t] = 1000000.0f;
    }
  }
}

// ---------------------------------------------------------------- per-line argmin assignment + lines2 output
__global__ __launch_bounds__(256) void k_lines(const float* __restrict__ lp,
                                               const float* __restrict__ jx,
                                               const float* __restrict__ jy,
                                               float4* __restrict__ lines4,
                                               int* __restrict__ iskeep,
                                               float* __restrict__ out_lines) {
  int b = blockIdx.y;
  int l = blockIdx.x * 256 + threadIdx.x;
  __shared__ float jxs[NTOPK], jys[NTOPK];
  for (int i = threadIdx.x; i < NTOPK; i += 256) {
    jxs[i] = jx[b * NTOPK + i];
    jys[i] = jy[b * NTOPK + i];
  }
  __syncthreads();
  int gl = b * HW + l;
  const float* L = lp + (size_t)gl * 4;
  float x1 = L[0], y1 = L[1], x2 = L[2], y2 = L[3];
  float bd1 = 3.4e38f, bd2 = 3.4e38f;
  int i1 = 0, i2 = 0;
  for (int j = 0; j < NTOPK; ++j) {
    float ax = __fsub_rn(x1, jxs[j]);
    float ay = __fsub_rn(y1, jys[j]);
    float d1 = __fadd_rn(__fmul_rn(ax, ax), __fmul_rn(ay, ay));
    if (d1 < bd1) { bd1 = d1; i1 = j; }
    float ex = __fsub_rn(x2, jxs[j]);
    float ey = __fsub_rn(y2, jys[j]);
    float d2 = __fadd_rn(__fmul_rn(ex, ex), __fmul_rn(ey, ey));
    if (d2 < bd2) { bd2 = d2; i2 = j; }
  }
  int imin = min(i1, i2), imax = max(i1, i2);
  float sx1 = jxs[imin], sy1 = jys[imin], sx2 = jxs[imax], sy2 = jys[imax];
  lines4[gl] = make_float4(sx1, sy1, sx2, sy2);
  iskeep[gl] = (imin < imax) ? 1 : 0;
  ((float4*)out_lines)[gl] = make_float4(sx1 * 4.0f, sy1 * 4.0f, sx2 * 4.0f, sy2 * 4.0f);
}

// ---------------------------------------------------------------- bilinear sample + maxpool
// 2 lines per block, 128 threads: t>>6 = line-in-block, t&63 = channel pair.
// grid.y = image count (b = b_base + blockIdx.y); xvec row = blockIdx.y*rows_per_b + (l-l0)
__global__ __launch_bounds__(128) void k_sample(const unsigned short* __restrict__ loi,
                                                const float4* __restrict__ lines4,
                                                unsigned short* __restrict__ xvec,
                                                int b_base, int l0, int rows_per_b) {
  __shared__ int   soff[2][32][4];
  __shared__ float swt[2][32][4];
  int b = b_base + blockIdx.y;
  int t = threadIdx.x;
  if (t < 64) {
    int li = t >> 5, k = t & 31;
    int l = l0 + blockIdx.x * 2 + li;
    float4 ln = lines4[b * HW + l];
    float tt = (float)k * (1.0f / 31.0f);
    float tc = 1.0f - tt;
    float px = ln.x * tt + ln.z * tc - 0.5f;
    float py = ln.y * tt + ln.w * tc - 0.5f;
    float px0 = fminf(fmaxf(floorf(px), 0.0f), 127.0f);
    float py0 = fminf(fmaxf(floorf(py), 0.0f), 127.0f);
    float px1 = fminf(px0 + 1.0f, 127.0f);
    float py1 = fminf(py0 + 1.0f, 127.0f);
    int ix0 = (int)px0, iy0 = (int)py0, ix1 = (int)px1, iy1 = (int)py1;
    float wy1 = __fsub_rn(py1, py), wy0 = __fsub_rn(py, py0);
    float wx1 = __fsub_rn(px1, px), wx0 = __fsub_rn(px, px0);
    soff[li][k][0] = (iy0 * WIDTH + ix0) * 128;
    soff[li][k][1] = (iy1 * WIDTH + ix0) * 128;
    soff[li][k][2] = (iy0 * WIDTH + ix1) * 128;
    soff[li][k][3] = (iy1 * WIDTH + ix1) * 128;
    swt[li][k][0] = __fmul_rn(wy1, wx1);   // wa -> r00
    swt[li][k][1] = __fmul_rn(wy0, wx1);   // wb -> r10
    swt[li][k][2] = __fmul_rn(wy1, wx0);   // wc -> r01
    swt[li][k][3] = __fmul_rn(wy0, wx0);   // wd -> r11
  }
  __syncthreads();
  int li = t >> 6, c2 = t & 63;            // channels 2*c2, 2*c2+1
  int l = l0 + blockIdx.x * 2 + li;
  const unsigned short* Lb = loi + (size_t)b * HW * 128 + (c2 << 1);
  float rm0 = -3.4e38f, rm1 = -3.4e38f;
  alignas(16) unsigned short outv[16];
#pragma unroll 4
  for (int k = 0; k < 32; ++k) {
    int4   o = *(const int4*)soff[li][k];
    float4 w = *(const float4*)swt[li][k];
    unsigned int u0 = *(const unsigned int*)(Lb + o.x);
    unsigned int u1 = *(const unsigned int*)(Lb + o.y);
    unsigned int u2 = *(const unsigned int*)(Lb + o.z);
    unsigned int u3 = *(const unsigned int*)(Lb + o.w);
    float2 v0 = bf2x2(u0), v1 = bf2x2(u1), v2 = bf2x2(u2), v3 = bf2x2(u3);
    float a0 = __fadd_rn(__fadd_rn(__fadd_rn(__fmul_rn(v0.x, w.x), __fmul_rn(v1.x, w.y)),
                                   __fmul_rn(v2.x, w.z)), __fmul_rn(v3.x, w.w));
    float a1 = __fadd_rn(__fadd_rn(__fadd_rn(__fmul_rn(v0.y, w.x), __fmul_rn(v1.y, w.y)),
                                   __fmul_rn(v2.y, w.z)), __fmul_rn(v3.y, w.w));
    rm0 = fmaxf(rm0, a0);
    rm1 = fmaxf(rm1, a1);
    if ((k & 3) == 3) {
      outv[k >> 2]       = f2bf(rm0);
      outv[8 + (k >> 2)] = f2bf(rm1);
      rm0 = -3.4e38f; rm1 = -3.4e38f;
    }
  }
  size_t xrow = (size_t)blockIdx.y * rows_per_b + (l - l0);
  unsigned short* dst = xvec + xrow * 1024 + c2 * 16;
  *(s16x8*)dst       = *(const s16x8*)outv;
  *(s16x8*)(dst + 8) = *(const s16x8*)(outv + 8);
}

// ---------------------------------------------------------------- shared FC K-loop: BM=256, BN=128, BK=32, 512 threads / 8 waves
// global_load_lds staging, double-buffered LDS, 1 barrier/iter.
__device__ __forceinline__ void fc_kloop(const unsigned short* __restrict__ A,
                                         const unsigned short* __restrict__ Bt,
                                         short* sm, int m0, int n0,
                                         f32x4 acc[4][4]) {
  const int K = 1024;
  int t = threadIdx.x, lane = t & 63, w = t >> 6;   // w 0..7
  int wm = w & 3, wn = w >> 2;
  int lr = lane & 15, ls = lane >> 4;

  const unsigned short* gA0 = A + (size_t)(m0 + w * 16 + lr) * K + ls * 8;
  const unsigned short* gA1 = A + (size_t)(m0 + (w + 8) * 16 + lr) * K + ls * 8;
  const unsigned short* gB  = Bt + (size_t)(n0 + w * 16 + lr) * K + ls * 8;
  int oA0 = w * 512 + lane * 8;
  int oA1 = (w + 8) * 512 + lane * 8;
  int oB  = 8192 + w * 512 + lane * 8;

  GLOAD_LDS16(gA0, sm + oA0);
  GLOAD_LDS16(gA1, sm + oA1);
  GLOAD_LDS16(gB,  sm + oB);
  __syncthreads();

  int cur = 0;
  for (int k0 = 0; k0 < K; k0 += 32) {
    int nxt = cur ^ 1;
    if (k0 + 32 < K) {
      int ko = k0 + 32;
      short* d = sm + nxt * 12288;
      GLOAD_LDS16(gA0 + ko, d + oA0);
      GLOAD_LDS16(gA1 + ko, d + oA1);
      GLOAD_LDS16(gB  + ko, d + oB);
    }
    const short* As = sm + cur * 12288;
    const short* Bs = As + 8192;
    s16x8 af[4], bfr[4];
#pragma unroll
    for (int mi = 0; mi < 4; ++mi) af[mi] = *(const s16x8*)(As + (wm * 4 + mi) * 512 + lane * 8);
#pragma unroll
    for (int ni = 0; ni < 4; ++ni) bfr[ni] = *(const s16x8*)(Bs + (wn * 4 + ni) * 512 + lane * 8);
#pragma unroll
    for (int mi = 0; mi < 4; ++mi)
#pragma unroll
      for (int ni = 0; ni < 4; ++ni)
        acc[mi][ni] = __builtin_amdgcn_mfma_f32_16x16x32_bf16(af[mi], bfr[ni], acc[mi][ni], 0, 0, 0);
    __syncthreads();
    cur = nxt;
  }
}

// ---------------------------------------------------------------- fc1: C = relu(A @ Bt^T + bias), bf16 out, 256x128 tile
__global__ __launch_bounds__(512) void k_fc1(const unsigned short* __restrict__ A,
                                             const unsigned short* __restrict__ Bt,
                                             const float* __restrict__ bias,
                                             unsigned short* __restrict__ C,
                                             int nm) {
  const int N = 1024;
  __shared__ __align__(16) short sm[24576];   // loop: 2x12288; epilogue pass: 128x136=17408
  int t = threadIdx.x, lane = t & 63, w = t >> 6;
  int wm = w & 3, wn = w >> 2;
  int lr = lane & 15, ls = lane >> 4;
  int m_idx, n_idx;
  fc_tile_map(blockIdx.x, nm, m_idx, n_idx);
  int m0 = m_idx * 256, n0 = n_idx * 128;

  f32x4 acc[4][4];
#pragma unroll
  for (int i = 0; i < 4; ++i)
#pragma unroll
    for (int j = 0; j < 4; ++j) acc[i][j] = (f32x4){0.f, 0.f, 0.f, 0.f};

  fc_kloop(A, Bt, sm, m0, n0, acc);
  __syncthreads();

  // two-pass LDS-staged epilogue (128 rows per pass), coalesced stores
  for (int p = 0; p < 2; ++p) {
    if ((wm >> 1) == p) {
#pragma unroll
      for (int ni = 0; ni < 4; ++ni) {
        int cl = wn * 64 + ni * 16 + lr;
        float bv = bias[n0 + cl];
#pragma unroll
        for (int mi = 0; mi < 4; ++mi) {
          int rl = (wm & 1) * 64 + mi * 16 + ls * 4;
#pragma unroll
          for (int r = 0; r < 4; ++r)
            sm[(rl + r) * 136 + cl] = (short)f2bf(fmaxf(acc[mi][ni][r] + bv, 0.0f));
        }
      }
    }
    __syncthreads();
    {
      int row = t >> 2, q = t & 3;
      const short* src = sm + row * 136 + q * 32;
      unsigned short* dst = C + (size_t)(m0 + p * 128 + row) * N + n0 + q * 32;
#pragma unroll
      for (int i = 0; i < 4; ++i)
        *(s16x8*)(dst + i * 8) = *(const s16x8*)(src + i * 8);
    }
    __syncthreads();
  }
}

// ---------------------------------------------------------------- fc2 fused with logits: per-n0 partial sums (no atomics)
// logp[(base+row)*8 + n_idx] = sum over this block's 128 cols of relu(...)*w3
__global__ __launch_bounds__(512) void k_fc2log(const unsigned short* __restrict__ A,
                                                const unsigned short* __restrict__ Bt,
                                                const float* __restrict__ bias,
                                                const float* __restrict__ w3,
                                                float* __restrict__ logp,
                                                int base, int nm) {
  __shared__ __align__(16) short sm[24576];
  int t = threadIdx.x, lane = t & 63, w = t >> 6;
  int wm = w & 3, wn = w >> 2;
  int lr = lane & 15, ls = lane >> 4;
  int m_idx, n_idx;
  fc_tile_map(blockIdx.x, nm, m_idx, n_idx);
  int m0 = m_idx * 256, n0 = n_idx * 128;

  f32x4 acc[4][4];
#pragma unroll
  for (int i = 0; i < 4; ++i)
#pragma unroll
    for (int j = 0; j < 4; ++j) acc[i][j] = (f32x4){0.f, 0.f, 0.f, 0.f};

  fc_kloop(A, Bt, sm, m0, n0, acc);

  // epilogue: psum[mi][r] = sum over this wave's 64 cols of relu(acc+b2)*w3
  float psum[4][4];
#pragma unroll
  for (int mi = 0; mi < 4; ++mi)
#pragma unroll
    for (int r = 0; r < 4; ++r) psum[mi][r] = 0.0f;
#pragma unroll
  for (int ni = 0; ni < 4; ++ni) {
    int col = n0 + wn * 64 + ni * 16 + lr;
    float bv = bias[col];
    float wv = w3[col];
#pragma unroll
    for (int mi = 0; mi < 4; ++mi)
#pragma unroll
      for (int r = 0; r < 4; ++r)
        psum[mi][r] += fmaxf(acc[mi][ni][r] + bv, 0.0f) * wv;
  }
  // the two wn waves covering the same rows sum via LDS
  __syncthreads();
  float* red = (float*)sm;    // 256 rows x 2
#pragma unroll
  for (int mi = 0; mi < 4; ++mi)
#pragma unroll
    for (int r = 0; r < 4; ++r) {
      float v = psum[mi][r];
      v += __shfl_xor(v, 1, 64);
      v += __shfl_xor(v, 2, 64);
      v += __shfl_xor(v, 4, 64);
      v += __shfl_xor(v, 8, 64);
      if (lr == 0) {
        int row = wm * 64 + mi * 16 + ls * 4 + r;
        red[row * 2 + wn] = v;
      }
    }
  __syncthreads();
  if (t < 256)
    logp[(size_t)(base + m0 + t) * 8 + n_idx] = red[t * 2] + red[t * 2 + 1];
}

// ---------------------------------------------------------------- final: reduce partials + sigmoid + keep
__global__ __launch_bounds__(256) void k_fin(const float* __restrict__ logp,
                                             const float* __restrict__ b3,
                                             const int* __restrict__ iskeep,
                                             float* __restrict__ oscore,
                                             float* __restrict__ okeep,
                                             int base) {
  int gl = base + blockIdx.x * 256 + threadIdx.x;
  const float4* p4 = (const float4*)(logp + (size_t)gl * 8);
  float4 a = p4[0], b = p4[1];
  float s = ((a.x + a.y) + (a.z + a.w)) + ((b.x + b.y) + (b.z + b.w));
  float sc = sigm(s + b3[0]);
  oscore[gl] = sc;
  okeep[gl] = (iskeep[gl] && sc > 0.05f) ? 1.0f : 0.0f;
}

// ================================================================ host
extern "C" void kernel_launch(void* const* d_in, const int* in_sizes, int n_in,
                              void* d_out, int out_size, void* d_ws, size_t ws_size,
                              hipStream_t stream) {
  const float* output     = (const float*)d_in[0];
  const float* features   = (const float*)d_in[1];
  const float* line_preds = (const float*)d_in[2];
  const float* conv_w     = (const float*)d_in[3];
  const float* conv_b     = (const float*)d_in[4];
  const float* w1         = (const float*)d_in[5];
  const float* b1         = (const float*)d_in[6];
  const float* w2         = (const float*)d_in[7];
  const float* b2         = (const float*)d_in[8];
  const float* w3         = (const float*)d_in[9];
  const float* b3         = (const float*)d_in[10];

  char* ws = (char*)d_ws;
  size_t off = 0;
  auto alloc = [&](size_t bytes) -> void* {
    void* p = ws + off;
    off += (bytes + 255) & ~(size_t)255;
    return p;
  };
  float* wt      = (float*)alloc((size_t)256 * 128 * 4);
  unsigned short* loi = (unsigned short*)alloc((size_t)NB * HW * 128 * 2);
  float* jloc    = (float*)alloc((size_t)NB * HW * 4);
  unsigned long long* keys = (unsigned long long*)alloc((size_t)NB * HW * 8);
  float* jx      = (float*)alloc((size_t)NB * NTOPK * 4);
  float* jy      = (float*)alloc((size_t)NB * NTOPK * 4);
  float4* lines4 = (float4*)alloc((size_t)NB * HW * 16);
  int* iskeep    = (int*)alloc((size_t)NB * HW * 4);
  float* logp    = (float*)alloc((size_t)NB * HW * 8 * 4);   // 8 partials per line
  unsigned short* w1b = (unsigned short*)alloc((size_t)1024 * 1024 * 2);   // [N][K] bf16
  unsigned short* w2b = (unsigned short*)alloc((size_t)1024 * 1024 * 2);
  size_t fixed = off;

  // pick activation size: merged (both images, M=32768) if it fits, else per-image chunks
  bool merged = (fixed + (size_t)2 * NB * HW * 1024 * 2 + 512 <= ws_size);
  int CH = 256;
  if (!merged) {
    const int cands[7] = {16384, 8192, 4096, 2048, 1024, 512, 256};
    for (int ci = 0; ci < 7; ++ci) {
      if (fixed + (size_t)2 * cands[ci] * 1024 * 2 + 512 <= ws_size) { CH = cands[ci]; break; }
    }
  }
  size_t actrows = merged ? (size_t)NB * HW : (size_t)CH;
  unsigned short* xvec = (unsigned short*)alloc(actrows * 1024 * 2);
  unsigned short* h1   = (unsigned short*)alloc(actrows * 1024 * 2);

  float* out_lines  = (float*)d_out;              // (B, L, 2, 2)
  float* out_scores = out_lines + (size_t)NB * HW * 4;
  float* out_keep   = out_scores + (size_t)NB * HW;

  k_transpose_w<<<128, 256, 0, stream>>>(conv_w, wt);
  k_wtrans<<<dim3(32, 32), 256, 0, stream>>>(w1, w1b);
  k_wtrans<<<dim3(32, 32), 256, 0, stream>>>(w2, w2b);
  k_loi<<<dim3(HW / 64, NB), 256, 0, stream>>>(features, wt, conv_b, loi);
  k_jloc<<<NB * HW / 256, 256, 0, stream>>>(output, jloc);
  k_nmskey<<<NB * HW / 256, 256, 0, stream>>>(jloc, keys);
  k_topk<<<NB, 1024, 0, stream>>>(keys, output, jx, jy);
  k_lines<<<dim3(HW / 256, NB), 256, 0, stream>>>(line_preds, jx, jy, lines4, iskeep, out_lines);

  if (merged) {
    int M = NB * HW, nm = M / 256;
    k_sample<<<dim3(HW / 2, NB), 128, 0, stream>>>(loi, lines4, xvec, 0, 0, HW);
    k_fc1<<<nm * 8, 512, 0, stream>>>(xvec, w1b, b1, h1, nm);
    k_fc2log<<<nm * 8, 512, 0, stream>>>(h1, w2b, b2, w3, logp, 0, nm);
    k_fin<<<M / 256, 256, 0, stream>>>(logp, b3, iskeep, out_scores, out_keep, 0);
  } else {
    int nchunk = HW / CH, nm = CH / 256;
    for (int b = 0; b < NB; ++b) {
      for (int ci = 0; ci < nchunk; ++ci) {
        int l0 = ci * CH;
        int base = b * HW + l0;
        k_sample<<<dim3(CH / 2, 1), 128, 0, stream>>>(loi, lines4, xvec, b, l0, CH);
        k_fc1<<<nm * 8, 512, 0, stream>>>(xvec, w1b, b1, h1, nm);
        k_fc2log<<<nm * 8, 512, 0, stream>>>(h1, w2b, b2, w3, logp, base, nm);
        k_fin<<<CH / 256, 256, 0, stream>>>(logp, b3, iskeep, out_scores, out_keep, base);
      }
    }
  }
}